// Round 1
// 243.118 us; speedup vs baseline: 1.0084x; 1.0084x over previous
//
#include <hip/hip_runtime.h>
#include <float.h>

#define T_TOTAL 32768
#define KC      8192
#define DIM     256

#define LOSS_IDX  ((size_t)T_TOTAL * DIM)      // 8388608
#define USAGE_IDX (LOSS_IDX + 1)

typedef short s16x8 __attribute__((ext_vector_type(8)));
typedef float f32x4 __attribute__((ext_vector_type(4)));

// ws layout (bytes):
#define WS_W2    0                 // f32[8192]
#define WS_FLAGS 32768             // i32[8192]
#define WS_CBF   65536             // u16[8192*256] = 4 MB

__device__ __forceinline__ unsigned short f2bf(float f) {
    unsigned int u = __float_as_uint(f);
    u += 0x7FFFu + ((u >> 16) & 1u);   // RTNE
    return (unsigned short)(u >> 16);
}

// ---------------------------------------------------------------------------
// prep: cb->bf16 + exact fp32 w2; flags zero (blocks 0..31); scalars (block 0)
__global__ __launch_bounds__(256) void vq_prep(const float* __restrict__ cb,
                                               unsigned short* __restrict__ cbb,
                                               float* __restrict__ w2,
                                               int* __restrict__ flags,
                                               float* __restrict__ out) {
    const int blk = blockIdx.x, tid = threadIdx.x;
    size_t i = (size_t)blk * 2048 + (size_t)tid * 8;
    float4 a = *(const float4*)(cb + i);
    float4 b = *(const float4*)(cb + i + 4);
    uint4 o;
    o.x = (unsigned)f2bf(a.x) | ((unsigned)f2bf(a.y) << 16);
    o.y = (unsigned)f2bf(a.z) | ((unsigned)f2bf(a.w) << 16);
    o.z = (unsigned)f2bf(b.x) | ((unsigned)f2bf(b.y) << 16);
    o.w = (unsigned)f2bf(b.z) | ((unsigned)f2bf(b.w) << 16);
    *(uint4*)(cbb + i) = o;
    float s = a.x * a.x + a.y * a.y + a.z * a.z + a.w * a.w
            + b.x * b.x + b.y * b.y + b.z * b.z + b.w * b.w;
    #pragma unroll
    for (int m = 1; m <= 16; m <<= 1) s += __shfl_xor(s, m);
    if ((tid & 31) == 0) w2[blk * 8 + (tid >> 5)] = s;
    if (blk < 32) flags[blk * 256 + tid] = 0;
    if (blk == 0 && tid == 0) { out[LOSS_IDX] = 0.0f; out[USAGE_IDX] = 0.0f; }
}

// ---------------------------------------------------------------------------
// main: block = 128 tokens x all 8192 codes, grid 256 (1 block/CU), 8 waves.
// wave w: wr=w>>2 token half (64 tokens, A in 128 regs), wc=w&3 code quarter.
// Window = 32 codes x 64 k = 4 KB, 256 windows. Wave-private 4-deep LDS
// buffers + register-pipelined fragments:
//   iter n: lgkm(0) [prior ds_reads retired -> buf[n&3] recyclable]
//           STAGE(n+4 -> buf[n&3])
//           vmcnt(8) [drains st(n+1); robust even if a staging group sinks]
//           ds_read frags(n+1) -> regB[(n+1)&1]
//           16 MFMAs on regB[n&1]   (all latencies pre-hidden)
// Dummy wrap-around staging keeps the vmcnt accounting uniform at the tail.
//
// R1 changes vs 245us baseline (theory: VALUBusy 36% ~ 143 VALU/iter is
// mostly recomputed addressing, serialized against the MFMA pipe at only
// 2 waves/SIMD):
//   - STAGE addresses strength-reduced: per-lane invariant base pointer
//     (note sl = ssl^(lr&7) = ssl^srow is q- and window-invariant), per-chunk
//     scalar offset ((c+1)&63)<<15; per-load cost = one 64-bit add.
//   - READFRAGS LDS addresses hoisted to 4 per-lane pointers; buffer select
//     is the compile-time +BP*2048 that folds into ds_read offset imm.
//   - s_setprio(1) around the MFMA cluster (waves are phase-independent,
//     attn-like regime where T5 pays).
//   - w2 fold pointer hoisted.
// Pipeline structure / waitcnt encodings / buffer rotation are IDENTICAL.
__global__ __launch_bounds__(512, 2) void vq_main(const unsigned short* __restrict__ cbb,
                                                  const float* __restrict__ w2g,
                                                  const float* __restrict__ z_e,
                                                  const float* __restrict__ cb,
                                                  float* __restrict__ out,
                                                  int* __restrict__ flags) {
    __shared__ unsigned short ca[8][4][2048];   // [wave][buf][4 KB] = 128 KB
    __shared__ unsigned long long smin[128];
    __shared__ float wls[8];

    const int tid  = threadIdx.x;
    const int lane = tid & 63;
    const int w    = tid >> 6;        // 0..7
    const int wr   = w >> 2;          // token half
    const int wc   = w & 3;           // code quarter
    const int quad = lane >> 4;
    const int l15  = lane & 15;
    const int t0   = blockIdx.x * 128;

    if (tid < 128) smin[tid] = ~0ULL;
    __syncthreads();                  // smin published before any wave's epilogue

    // staging: window WIN (0..255): chunk _c=WIN>>2 (codes _c*128+wc*32+lr),
    // k-window _kw=WIN&3 (k in [_kw*64, _kw*64+64)). 4 loads x 1 KB, each
    // covering 8 rows x 128 B. Source k-slot XOR-swizzled by row for
    // conflict-free ds_read_b128 later.
    const int srow = lane >> 3;       // 0..7
    const int ssl  = lane & 7;        // LDS slot position
    // per-lane invariant global base: (wc*32 + srow)*DIM + (ssl^srow)*8.
    // full address for (chunk C, kw KW, quarter q):
    //   pstage + C*32768 + KW*64 + q*2048            (elements, verified ==
    //   (C*128 + wc*32 + q*8 + srow)*DIM + KW*64 + (ssl^srow)*8)
    const unsigned short* pstage = cbb + (wc * 32 + srow) * DIM + (ssl ^ srow) * 8;

    #define STAGE(PC, KW, BP)                                                           \
        {                                                                               \
            _Pragma("unroll")                                                           \
            for (int q = 0; q < 4; ++q) {                                               \
                __builtin_amdgcn_global_load_lds(                                       \
                    (const __attribute__((address_space(1))) void*)((PC) + (KW) * 64 + q * 2048), \
                    (__attribute__((address_space(3))) void*)(&ca[w][BP][q * 512]),     \
                    16, 0, 0);                                                          \
            }                                                                           \
        }

    // 4 hoisted per-lane LDS fragment pointers (kk,j); buffer select BP is a
    // compile-time +BP*2048 elements -> folds into ds_read offset immediate.
    const unsigned short* fragp[4];
    #pragma unroll
    for (int kk = 0; kk < 2; ++kk)
        #pragma unroll
        for (int j = 0; j < 2; ++j) {
            int row = j * 16 + l15;
            int sl = (kk * 4 + quad) ^ (l15 & 7);
            fragp[kk * 2 + j] = &ca[w][0][row * 64 + sl * 8];
        }

    #define READFRAGS(FB, BP)                                                           \
        {                                                                               \
            _Pragma("unroll")                                                           \
            for (int f = 0; f < 4; ++f)                                                 \
                (FB)[f] = *(const s16x8*)(fragp[f] + (BP) * 2048);                      \
        }

    // prologue: stage windows 0..3, then build A from fp32 z_e
    STAGE(pstage, 0, 0); STAGE(pstage, 1, 1); STAGE(pstage, 2, 2); STAGE(pstage, 3, 3);
    s16x8 af[4][8];
    #pragma unroll
    for (int i = 0; i < 4; ++i) {
        #pragma unroll
        for (int ks = 0; ks < 8; ++ks) {
            const float* p = z_e + (size_t)(t0 + wr * 64 + i * 16 + l15) * DIM + ks * 32 + quad * 8;
            float4 a = *(const float4*)p;
            float4 b = *(const float4*)(p + 4);
            s16x8 v;
            v[0] = (short)f2bf(a.x); v[1] = (short)f2bf(a.y);
            v[2] = (short)f2bf(a.z); v[3] = (short)f2bf(a.w);
            v[4] = (short)f2bf(b.x); v[5] = (short)f2bf(b.y);
            v[6] = (short)f2bf(b.z); v[7] = (short)f2bf(b.w);
            af[i][ks] = v;
        }
    }

    float best[4][4];
    int   bidx[4][4];
    #pragma unroll
    for (int i = 0; i < 4; ++i)
        #pragma unroll
        for (int r = 0; r < 4; ++r) { best[i][r] = FLT_MAX; bidx[i][r] = 0x7FFFFFFF; }

    // hoisted w2 fold pointer: w2v(c, j) = pw2[c*128 + j*16]
    const float* pw2 = w2g + wc * 32 + l15;

    // prime: window 0 frags into regB[0] (vmcnt(12): st0..3 + A outstanding,
    // leaves newest 12 -> st0 certainly drained)
    s16x8 regB[2][4];
    __builtin_amdgcn_s_waitcnt(0x0F7C);   // vmcnt(12), lgkm/exp unconstrained
    READFRAGS(regB[0], 0);

    for (int c = 0; c < 64; ++c) {
        f32x4 acc[4][2];
        #pragma unroll
        for (int i = 0; i < 4; ++i)
            #pragma unroll
            for (int j = 0; j < 2; ++j) acc[i][j] = (f32x4){0.f, 0.f, 0.f, 0.f};

        // next-chunk staging base (dummy wrap at c=63 keeps accounting uniform)
        const unsigned short* pcn = pstage + ((size_t)((c + 1) & 63) << 15);

        #pragma unroll
        for (int kw = 0; kw < 4; ++kw) {
            // n = c*4 + kw; n&3 == kw; (n+1)&3 == (kw+1)&3; (n+1)&1 == (kw+1)&1
            // prior ds_reads retired -> buf[kw] is recyclable for staging
            __builtin_amdgcn_s_waitcnt(0xC07F);   // lgkmcnt(0), vmcnt/exp unconstrained
            STAGE(pcn, kw, kw);                   // window n+4 -> buf[n&3]
            // drain staging of window n+1 (robust: st(n+2)+st(n+3)=8 newer)
            __builtin_amdgcn_s_waitcnt(0x0F78);   // vmcnt(8), lgkm/exp unconstrained
            READFRAGS(regB[(kw + 1) & 1], (kw + 1) & 3);
            // 16 MFMAs on window n (fragments read one iteration ago)
            const s16x8* cur = regB[kw & 1];
            __builtin_amdgcn_s_setprio(1);
            #pragma unroll
            for (int kk = 0; kk < 2; ++kk)
                #pragma unroll
                for (int i = 0; i < 4; ++i)
                    #pragma unroll
                    for (int j = 0; j < 2; ++j)
                        acc[i][j] = __builtin_amdgcn_mfma_f32_16x16x32_bf16(af[i][kw * 2 + kk], cur[kk * 2 + j], acc[i][j], 0, 0, 0);
            __builtin_amdgcn_s_setprio(0);
        }

        // fold chunk c into running argmin: score = w2[col] - 2*dot
        #pragma unroll
        for (int j = 0; j < 2; ++j) {
            int col = c * 128 + wc * 32 + j * 16 + l15;
            float w2v = pw2[c * 128 + j * 16];
            #pragma unroll
            for (int i = 0; i < 4; ++i)
                #pragma unroll
                for (int r = 0; r < 4; ++r) {
                    float s = fmaf(-2.0f, acc[i][j][r], w2v);
                    if (s < best[i][r]) { best[i][r] = s; bidx[i][r] = col; }  // ascending col: < keeps lowest
                }
        }
    }

    // cross-lane argmin over the 16 cols held per token row, then merge quarters
    #pragma unroll
    for (int i = 0; i < 4; ++i)
        #pragma unroll
        for (int r = 0; r < 4; ++r) {
            float b = best[i][r]; int ix = bidx[i][r];
            #pragma unroll
            for (int m = 1; m < 16; m <<= 1) {
                float ob = __shfl_xor(b, m);
                int   oi = __shfl_xor(ix, m);
                if (ob < b || (ob == b && oi < ix)) { b = ob; ix = oi; }
            }
            if (l15 == 0) {
                unsigned int fb = __float_as_uint(b);
                fb = (fb & 0x80000000u) ? ~fb : (fb | 0x80000000u);   // monotonic key
                unsigned long long key = ((unsigned long long)fb << 32) | (unsigned int)ix;
                atomicMin(&smin[wr * 64 + i * 16 + quad * 4 + r], key);
            }
        }
    __syncthreads();   // all waves' argmin merged before gather

    // fused gather + loss + flags: wave w -> tokens [w*16, w*16+16)
    float lsum = 0.0f;
    for (int t = w * 16; t < w * 16 + 16; ++t) {
        int tok = t0 + t;
        int k = (int)(unsigned int)(smin[t] & 0xFFFFFFFFull);
        if (lane == 0) flags[k] = 1;   // benign race
        float4 cv = *(const float4*)(cb + (size_t)k * DIM + lane * 4);
        float4 zv = *(const float4*)(z_e + (size_t)tok * DIM + lane * 4);
        float dx = zv.x - cv.x, dy = zv.y - cv.y, dz = zv.z - cv.z, dw = zv.w - cv.w;
        lsum += dx * dx + dy * dy + dz * dz + dw * dw;
        *(float4*)(out + (size_t)tok * DIM + lane * 4) = cv;
    }
    #pragma unroll
    for (int m = 32; m >= 1; m >>= 1) lsum += __shfl_xor(lsum, m);
    if (lane == 0) wls[w] = lsum;
    __syncthreads();
    if (tid == 0) {
        float bsum = 0.0f;
        #pragma unroll
        for (int q = 0; q < 8; ++q) bsum += wls[q];
        // loss = codebook + 0.25*commitment = 1.25 * mean(diff^2)
        atomicAdd(out + LOSS_IDX, bsum * (1.25f / (float)LOSS_IDX));
    }
}

// ---------------------------------------------------------------------------
__global__ __launch_bounds__(256) void vq_usage(const int* __restrict__ flags,
                                                float* __restrict__ out) {
    __shared__ int ws[4];
    int tid = threadIdx.x;
    int s = 0;
    for (int i = tid; i < KC; i += 256) s += flags[i];
    #pragma unroll
    for (int m = 32; m >= 1; m >>= 1) s += __shfl_xor(s, m);
    if ((tid & 63) == 0) ws[tid >> 6] = s;
    __syncthreads();
    if (tid == 0) out[USAGE_IDX] = (float)(ws[0] + ws[1] + ws[2] + ws[3]) / (float)KC;
}

// ---------------------------------------------------------------------------
extern "C" void kernel_launch(void* const* d_in, const int* in_sizes, int n_in,
                              void* d_out, int out_size, void* d_ws, size_t ws_size,
                              hipStream_t stream) {
    (void)in_sizes; (void)n_in; (void)out_size; (void)ws_size;
    const float* z_e = (const float*)d_in[0];
    const float* cb  = (const float*)d_in[1];
    float* out = (float*)d_out;

    char* ws = (char*)d_ws;
    float* w2    = (float*)(ws + WS_W2);
    int*   flags = (int*)(ws + WS_FLAGS);
    unsigned short* cbb = (unsigned short*)(ws + WS_CBF);

    vq_prep<<<KC / 8, 256, 0, stream>>>(cb, cbb, w2, flags, out);
    vq_main<<<T_TOTAL / 128, 512, 0, stream>>>(cbb, w2, z_e, cb, out, flags);
    vq_usage<<<1, 256, 0, stream>>>(flags, out);
}